// Round 8
// baseline (500.477 us; speedup 1.0000x reference)
//
#include <hip/hip_runtime.h>

#define NUM_USERS 120000
#define NUM_ITEMS 30000
#define NUM_NODES 150000   // NUM_USERS + NUM_ITEMS
#define EMBED_DIM 64
#define N_LAYERS 3
#define N_EDGES 4000000

#define BW_SHIFT 9                                     // 512 rows per bucket
#define BW_ROWS (1 << BW_SHIFT)
#define BW_MASK (BW_ROWS - 1)
#define NBUCK ((NUM_NODES + BW_MASK) >> BW_SHIFT)      // 293
#define BUCK_CAP 16000   // mean 13653, sd ~117 -> >20 sigma headroom
#define SUB_E 4096       // edges per LDS sub-tile in bucket_bin2

typedef float  f4v  __attribute__((ext_vector_type(4)));
typedef unsigned short us8v __attribute__((ext_vector_type(8)));

// ---------------- bf16 + nontemporal helpers ----------------

__device__ __forceinline__ float bf2f(unsigned short u) {
    union { unsigned int i; float f; } v;
    v.i = ((unsigned int)u) << 16;
    return v.f;
}
__device__ __forceinline__ unsigned short f2bf(float f) {
    union { float f; unsigned int i; } v;
    v.f = f;
    unsigned int u = v.i;
    u += 0x7FFFu + ((u >> 16) & 1u);   // round to nearest even
    return (unsigned short)(u >> 16);
}
__device__ __forceinline__ int2 ntload_i2(const int2* p) {
    union { long long l; int2 v; } u;
    u.l = __builtin_nontemporal_load((const long long*)p);
    return u.v;
}
__device__ __forceinline__ void ntstore_i2(int2* p, int2 v) {
    union { long long l; int2 v; } u;
    u.v = v;
    __builtin_nontemporal_store(u.l, (long long*)p);
}
__device__ __forceinline__ float4 ntload_f4(const float4* p) {
    union { f4v a; float4 b; } u;
    u.a = __builtin_nontemporal_load((const f4v*)p);
    return u.b;
}
__device__ __forceinline__ void ntstore_f4(float4* p, float4 v) {
    union { f4v a; float4 b; } u;
    u.b = v;
    __builtin_nontemporal_store(u.a, (f4v*)p);
}

// ---------------- small utils ----------------

__global__ void zero_ints(int* __restrict__ p, int n) {
    int i = blockIdx.x * blockDim.x + threadIdx.x;
    int stride = gridDim.x * blockDim.x;
    for (; i < n; i += stride) p[i] = 0;
}

// f32 table -> bf16 table
__global__ void conv_bf(const float4* __restrict__ src, ushort4* __restrict__ dst,
                        int n4) {
    int i = blockIdx.x * blockDim.x + threadIdx.x;
    int stride = gridDim.x * blockDim.x;
    for (; i < n4; i += stride) {
        float4 v = src[i];
        ushort4 q;
        q.x = f2bf(v.x); q.y = f2bf(v.y); q.z = f2bf(v.z); q.w = f2bf(v.w);
        dst[i] = q;
    }
}

// ---------------- CSR build ----------------

// Phase A v2: LDS sub-tile sort. Per 4096-edge sub-tile: LDS hist -> LDS scan
// -> per-bucket global reservation -> rank-scatter into LDS -> linear copy-out.
// Stage lines get all their writes in one burst (no eviction re-write).
// record: x = (local_r << 18) | col, y = w bits
__global__ void __launch_bounds__(256)
bucket_bin2(const int* __restrict__ row, const int* __restrict__ col,
            const float* __restrict__ w,
            int* __restrict__ gcnt, int2* __restrict__ stage, int nEdges) {
    __shared__ int2 lbuf[SUB_E];       // 32 KB records
    __shared__ int  ldst[SUB_E];       // 16 KB absolute dst (or -1)
    __shared__ int  hist[NBUCK];
    __shared__ int  cur[NBUCK];
    __shared__ int  dlt[NBUCK];
    __shared__ int  s0[512], s1[512];

    int nSub = (nEdges + SUB_E - 1) / SUB_E;
    for (int s = blockIdx.x; s < nSub; s += gridDim.x) {
        int e0 = s * SUB_E;
        int n = nEdges - e0; if (n > SUB_E) n = SUB_E;

        for (int j = threadIdx.x; j < NBUCK; j += 256) hist[j] = 0;
        __syncthreads();
        for (int i = threadIdx.x; i < n; i += 256)
            atomicAdd(&hist[row[e0 + i] >> BW_SHIFT], 1);
        __syncthreads();

        // inclusive scan of hist into a[] (512-wide Hillis-Steele)
        for (int j = threadIdx.x; j < 512; j += 256)
            s0[j] = (j < NBUCK) ? hist[j] : 0;
        __syncthreads();
        int *a = s0, *bb = s1;
        for (int off = 1; off < 512; off <<= 1) {
            for (int j = threadIdx.x; j < 512; j += 256) {
                int x = a[j];
                if (j >= off) x += a[j - off];
                bb[j] = x;
            }
            __syncthreads();
            int* t = a; a = bb; bb = t;
        }
        // reserve global space per bucket; cursor = local exclusive start
        for (int j = threadIdx.x; j < NBUCK; j += 256) {
            int c = hist[j];
            int ls = j ? a[j - 1] : 0;
            cur[j] = ls;
            int g = c ? atomicAdd(&gcnt[j], c) : 0;
            dlt[j] = j * BUCK_CAP + g - ls;   // absolute dst = dlt + lpos
        }
        __syncthreads();
        // rank-scatter into LDS
        for (int i = threadIdx.x; i < n; i += 256) {
            int r = row[e0 + i];
            int b = r >> BW_SHIFT;
            int lpos = atomicAdd(&cur[b], 1);
            lbuf[lpos] = make_int2(((r & BW_MASK) << 18) | col[e0 + i],
                                   __float_as_int(w[e0 + i]));
            int d = dlt[b] + lpos;
            ldst[lpos] = (d - b * BUCK_CAP < BUCK_CAP) ? d : -1;
        }
        __syncthreads();
        // linear copy-out: bucket-grouped bursts, write-combined
        for (int j = threadIdx.x; j < n; j += 256) {
            int d = ldst[j];
            if (d >= 0) ntstore_i2(&stage[d], lbuf[j]);
        }
        __syncthreads();
    }
}

// scan 293 bucket counts -> bstart[0..NBUCK]; also rs[NUM_NODES] = total
__global__ void bucket_scan(const int* __restrict__ gcnt, int* __restrict__ bstart,
                            int* __restrict__ rs) {
    __shared__ int s0[512], s1[512];
    int tid = threadIdx.x;
    int v = 0;
    if (tid < NBUCK) { v = gcnt[tid]; if (v > BUCK_CAP) v = BUCK_CAP; }
    s0[tid] = v;
    __syncthreads();
    int* a = s0; int* bb = s1;
    for (int off = 1; off < 512; off <<= 1) {
        int x = a[tid];
        if (tid >= off) x += a[tid - off];
        bb[tid] = x;
        __syncthreads();
        int* t = a; a = bb; bb = t;
    }
    if (tid == 0) bstart[0] = 0;
    if (tid < NBUCK) bstart[tid + 1] = a[tid];
    if (tid == 0) rs[NUM_NODES] = a[NBUCK - 1];
}

// Phase B: one block per bucket. LDS 512-row hist + scan -> rs[] + final CSR.
__global__ void __launch_bounds__(256)
bucket_scatter(const int2* __restrict__ stage, const int* __restrict__ gcnt,
               const int* __restrict__ bstart, int* __restrict__ rs,
               int2* __restrict__ csr) {
    __shared__ int s0[BW_ROWS], s1[BW_ROWS];
    int b = blockIdx.x;
    int tid = threadIdx.x;
    int nrec = gcnt[b]; if (nrec > BUCK_CAP) nrec = BUCK_CAP;
    int base = bstart[b];
    const int2* st = stage + (size_t)b * BUCK_CAP;
    int baseRow = b << BW_SHIFT;
    int rows = NUM_NODES - baseRow; if (rows > BW_ROWS) rows = BW_ROWS;

    for (int j = tid; j < BW_ROWS; j += 256) s0[j] = 0;
    __syncthreads();
    for (int i = tid; i < nrec; i += 256) atomicAdd(&s0[st[i].x >> 18], 1);
    __syncthreads();

    int* a = s0; int* bb = s1;
    for (int off = 1; off < BW_ROWS; off <<= 1) {
        for (int j = tid; j < BW_ROWS; j += 256) {
            int x = a[j];
            if (j >= off) x += a[j - off];
            bb[j] = x;
        }
        __syncthreads();
        int* t = a; a = bb; bb = t;
    }

    for (int r = tid; r < rows; r += 256)
        rs[baseRow + r] = base + (r ? a[r - 1] : 0);

    for (int j = tid; j < BW_ROWS; j += 256) bb[j] = 0;   // rank counters
    __syncthreads();
    for (int i = tid; i < nrec; i += 256) {
        int2 rec = st[i];
        int r = rec.x >> 18;
        int rank = atomicAdd(&bb[r], 1);
        ntstore_i2(&csr[base + (r ? a[r - 1] : 0) + rank],
                   make_int2(rec.x & 0x3FFFF, rec.y));
    }
}

// ---------------- CSR propagate (bf16, 8 lanes/node, ushort8/lane) ----------
// acc[d] = sum_e w[e] * xb[col[e]][d]; out = (addIn + acc)*scale; yb = bf16(acc)
__global__ void __launch_bounds__(256)
lgcn_prop_bf8(const us8v* __restrict__ xb,
              const int* __restrict__ rs,
              const int2* __restrict__ csr,
              us8v* __restrict__ yb,
              const float4* __restrict__ addIn,
              float4* __restrict__ out,
              float scale, int nNodes, int writeY) {
    int gtid = blockIdx.x * blockDim.x + threadIdx.x;
    int node = gtid >> 3;          // 8 lanes per node
    int sub  = threadIdx.x & 7;    // dims [sub*8, sub*8+8)
    if (node >= nNodes) return;
    int s = rs[node], e = rs[node + 1];
    float acc[8] = {0.f, 0.f, 0.f, 0.f, 0.f, 0.f, 0.f, 0.f};

    int base = s;
    for (; base + 8 <= e; base += 8) {
        int2 cw = ntload_i2(&csr[base + sub]);   // 64B coalesced per group
#pragma unroll
        for (int j = 0; j < 8; ++j) {
            int bc   = __shfl(cw.x, j, 8);
            float bw = __int_as_float(__shfl(cw.y, j, 8));
            us8v v = xb[(size_t)bc * 8 + sub];   // 16B/lane, 128B/group
#pragma unroll
            for (int k = 0; k < 8; ++k)
                acc[k] = fmaf(bf2f(v[k]), bw, acc[k]);
        }
    }
    if (base < e) {
        int idx = base + sub;
        int2 cw = (idx < e) ? ntload_i2(&csr[idx]) : make_int2(0, 0);
        int nn = e - base;
        for (int j = 0; j < nn; ++j) {
            int bc   = __shfl(cw.x, j, 8);
            float bw = __int_as_float(__shfl(cw.y, j, 8));
            us8v v = xb[(size_t)bc * 8 + sub];
#pragma unroll
            for (int k = 0; k < 8; ++k)
                acc[k] = fmaf(bf2f(v[k]), bw, acc[k]);
        }
    }

    size_t o8 = (size_t)node * 8 + sub;   // ushort8 units
    if (writeY) {
        us8v q;
#pragma unroll
        for (int k = 0; k < 8; ++k) q[k] = f2bf(acc[k]);
        __builtin_nontemporal_store(q, &yb[o8]);
    }
    size_t o4 = o8 * 2;                   // float4 units
    float4 a0 = ntload_f4(&addIn[o4]);
    float4 a1 = ntload_f4(&addIn[o4 + 1]);
    a0.x = (a0.x + acc[0]) * scale;
    a0.y = (a0.y + acc[1]) * scale;
    a0.z = (a0.z + acc[2]) * scale;
    a0.w = (a0.w + acc[3]) * scale;
    a1.x = (a1.x + acc[4]) * scale;
    a1.y = (a1.y + acc[5]) * scale;
    a1.z = (a1.z + acc[6]) * scale;
    a1.w = (a1.w + acc[7]) * scale;
    ntstore_f4(&out[o4], a0);
    ntstore_f4(&out[o4 + 1], a1);
}

// ---------------- fallback (atomic) path kernels ----------------

__global__ void lgcn_init(const float4* __restrict__ emb,
                          float4* __restrict__ x,
                          float4* __restrict__ out, int n4) {
    int i = blockIdx.x * blockDim.x + threadIdx.x;
    int stride = gridDim.x * blockDim.x;
    for (; i < n4; i += stride) {
        float4 v = emb[i];
        x[i] = v;
        out[i] = v;
    }
}

__global__ void lgcn_zero(float4* __restrict__ y, int n4) {
    int i = blockIdx.x * blockDim.x + threadIdx.x;
    int stride = gridDim.x * blockDim.x;
    float4 z = make_float4(0.f, 0.f, 0.f, 0.f);
    for (; i < n4; i += stride) y[i] = z;
}

__global__ void lgcn_edge(const float* __restrict__ x,
                          const float* __restrict__ w,
                          const int* __restrict__ row,
                          const int* __restrict__ col,
                          float* __restrict__ y, int nEdges) {
    int tid = blockIdx.x * blockDim.x + threadIdx.x;
    int wave = tid >> 6;
    int lane = threadIdx.x & 63;
    int nWaves = (gridDim.x * blockDim.x) >> 6;
    for (int e = wave; e < nEdges; e += nWaves) {
        int r = row[e];
        int c = col[e];
        float wt = w[e];
        float v = x[(size_t)c * EMBED_DIM + lane] * wt;
        atomicAdd(&y[(size_t)r * EMBED_DIM + lane], v);
    }
}

__global__ void lgcn_accum(const float4* __restrict__ y,
                           float4* __restrict__ out, float scale, int n4) {
    int i = blockIdx.x * blockDim.x + threadIdx.x;
    int stride = gridDim.x * blockDim.x;
    for (; i < n4; i += stride) {
        float4 o = out[i];
        float4 v = y[i];
        o.x = (o.x + v.x) * scale;
        o.y = (o.y + v.y) * scale;
        o.z = (o.z + v.z) * scale;
        o.w = (o.w + v.w) * scale;
        out[i] = o;
    }
}

// ---------------- launch ----------------

extern "C" void kernel_launch(void* const* d_in, const int* in_sizes, int n_in,
                              void* d_out, int out_size, void* d_ws, size_t ws_size,
                              hipStream_t stream) {
    const float* emb = (const float*)d_in[0];
    const float* ew  = (const float*)d_in[1];
    const int*   row = (const int*)d_in[2];
    const int*   col = (const int*)d_in[3];
    float* out = (float*)d_out;

    const size_t tableElems = (size_t)NUM_NODES * EMBED_DIM;   // 9.6M
    const int n4 = (int)(tableElems / 4);                      // 2.4M

    // workspace layout
    char* ws = (char*)d_ws;
    size_t off = 0;
    auto alloc = [&](size_t bytes) {
        char* p = ws + off;
        off += (bytes + 255) & ~(size_t)255;
        return p;
    };
    ushort4* yAb   = (ushort4*)alloc(tableElems * 2);            // 19.2 MB
    ushort4* yBb   = (ushort4*)alloc(tableElems * 2);            // 19.2 MB
    int2*    csr   = (int2*)   alloc((size_t)N_EDGES * 8);       // 32 MB
    int2*    stage = (int2*)   alloc((size_t)NBUCK * BUCK_CAP * 8); // 37.5 MB
    int*     rs    = (int*)    alloc((size_t)(NUM_NODES + 32) * 4);
    int*     bstart= (int*)    alloc((size_t)(NBUCK + 8) * 4);
    int*     gcnt  = (int*)    alloc((size_t)(NBUCK + 8) * 4);
    size_t need = off;
    // emb_bf aliases stage (19.2 <= 37.5 MB): stage dead after bucket_scatter
    ushort4* embb = (ushort4*)stage;

    if (ws_size >= need) {
        // ---- CSR build ----
        zero_ints<<<2, 256, 0, stream>>>(gcnt, NBUCK);
        bucket_bin2<<<512, 256, 0, stream>>>(row, col, ew, gcnt, stage, N_EDGES);
        bucket_scan<<<1, 512, 0, stream>>>(gcnt, bstart, rs);
        bucket_scatter<<<NBUCK, 256, 0, stream>>>(stage, gcnt, bstart, rs, csr);

        // ---- emb -> bf16 (overwrites stage region, now dead) ----
        conv_bf<<<2048, 256, 0, stream>>>((const float4*)emb, (ushort4*)embb, n4);

        // ---- propagate: 3 layers, 8 lanes per node ----
        const int propBlocks = (NUM_NODES * 8 + 255) / 256;
        // layer 1: x = emb_bf, out = emb + y1, y1 -> yAb
        lgcn_prop_bf8<<<propBlocks, 256, 0, stream>>>((const us8v*)embb, rs, csr,
                                                      (us8v*)yAb,
                                                      (const float4*)emb,
                                                      (float4*)out,
                                                      1.0f, NUM_NODES, 1);
        // layer 2: x = y1, out += y2, y2 -> yBb
        lgcn_prop_bf8<<<propBlocks, 256, 0, stream>>>((const us8v*)yAb, rs, csr,
                                                      (us8v*)yBb,
                                                      (const float4*)out,
                                                      (float4*)out,
                                                      1.0f, NUM_NODES, 1);
        // layer 3: x = y2, out = (out + y3) / 4
        lgcn_prop_bf8<<<propBlocks, 256, 0, stream>>>((const us8v*)yBb, rs, csr,
                                                      (us8v*)yAb,
                                                      (const float4*)out,
                                                      (float4*)out,
                                                      1.0f / (N_LAYERS + 1),
                                                      NUM_NODES, 0);
    } else {
        // ---- fallback: atomic path (round-1 proven), f32 buffers from ws ----
        float* x = (float*)d_ws;
        float* y = x + tableElems;
        lgcn_init<<<2048, 256, 0, stream>>>((const float4*)emb, (float4*)x,
                                            (float4*)out, n4);
        for (int l = 0; l < N_LAYERS; ++l) {
            lgcn_zero<<<2048, 256, 0, stream>>>((float4*)y, n4);
            lgcn_edge<<<4096, 256, 0, stream>>>(x, ew, row, col, y, N_EDGES);
            float scale = (l == N_LAYERS - 1) ? 1.0f / (N_LAYERS + 1) : 1.0f;
            lgcn_accum<<<2048, 256, 0, stream>>>((const float4*)y, (float4*)out,
                                                 scale, n4);
            float* t = x; x = y; y = t;
        }
    }
}

// Round 9
// 377.794 us; speedup vs baseline: 1.3247x; 1.3247x over previous
//
#include <hip/hip_runtime.h>

#define NUM_USERS 120000
#define NUM_ITEMS 30000
#define NUM_NODES 150000   // NUM_USERS + NUM_ITEMS
#define EMBED_DIM 64
#define N_LAYERS 3
#define N_EDGES 4000000

#define BW_SHIFT 9                                     // 512 rows per bucket
#define BW_ROWS (1 << BW_SHIFT)
#define BW_MASK (BW_ROWS - 1)
#define NBUCK ((NUM_NODES + BW_MASK) >> BW_SHIFT)      // 293
#define BUCK_CAP 16000   // mean 13653, sd ~117 -> >20 sigma headroom
#define SUB_E 4096       // edges per LDS sub-tile in bucket_bin2

typedef unsigned short us8v __attribute__((ext_vector_type(8)));

// ---------------- bf16 helpers ----------------

__device__ __forceinline__ float bf2f(unsigned short u) {
    union { unsigned int i; float f; } v;
    v.i = ((unsigned int)u) << 16;
    return v.f;
}
__device__ __forceinline__ unsigned short f2bf(float f) {
    union { float f; unsigned int i; } v;
    v.f = f;
    unsigned int u = v.i;
    u += 0x7FFFu + ((u >> 16) & 1u);   // round to nearest even
    return (unsigned short)(u >> 16);
}

// ---------------- small utils ----------------

__global__ void zero_ints(int* __restrict__ p, int n) {
    int i = blockIdx.x * blockDim.x + threadIdx.x;
    int stride = gridDim.x * blockDim.x;
    for (; i < n; i += stride) p[i] = 0;
}

// f32 table -> bf16 table
__global__ void conv_bf(const float4* __restrict__ src, ushort4* __restrict__ dst,
                        int n4) {
    int i = blockIdx.x * blockDim.x + threadIdx.x;
    int stride = gridDim.x * blockDim.x;
    for (; i < n4; i += stride) {
        float4 v = src[i];
        ushort4 q;
        q.x = f2bf(v.x); q.y = f2bf(v.y); q.z = f2bf(v.z); q.w = f2bf(v.w);
        dst[i] = q;
    }
}

// ---------------- CSR build ----------------

// Phase A v2: LDS sub-tile sort. Per 4096-edge sub-tile: LDS hist -> LDS scan
// -> per-bucket global reservation -> rank-scatter into LDS -> linear copy-out.
// Stage lines get all their writes in one burst (write-combined in L2).
// record: x = (local_r << 18) | col, y = w bits
__global__ void __launch_bounds__(256)
bucket_bin2(const int* __restrict__ row, const int* __restrict__ col,
            const float* __restrict__ w,
            int* __restrict__ gcnt, int2* __restrict__ stage, int nEdges) {
    __shared__ int2 lbuf[SUB_E];       // 32 KB records
    __shared__ int  ldst[SUB_E];       // 16 KB absolute dst (or -1)
    __shared__ int  hist[NBUCK];
    __shared__ int  cur[NBUCK];
    __shared__ int  dlt[NBUCK];
    __shared__ int  s0[512], s1[512];

    int nSub = (nEdges + SUB_E - 1) / SUB_E;
    for (int s = blockIdx.x; s < nSub; s += gridDim.x) {
        int e0 = s * SUB_E;
        int n = nEdges - e0; if (n > SUB_E) n = SUB_E;

        for (int j = threadIdx.x; j < NBUCK; j += 256) hist[j] = 0;
        __syncthreads();
        for (int i = threadIdx.x; i < n; i += 256)
            atomicAdd(&hist[row[e0 + i] >> BW_SHIFT], 1);
        __syncthreads();

        // inclusive scan of hist (512-wide Hillis-Steele, double-buffered)
        for (int j = threadIdx.x; j < 512; j += 256)
            s0[j] = (j < NBUCK) ? hist[j] : 0;
        __syncthreads();
        int *a = s0, *bb = s1;
        for (int off = 1; off < 512; off <<= 1) {
            for (int j = threadIdx.x; j < 512; j += 256) {
                int x = a[j];
                if (j >= off) x += a[j - off];
                bb[j] = x;
            }
            __syncthreads();
            int* t = a; a = bb; bb = t;
        }
        // reserve global space per bucket; cursor = local exclusive start
        for (int j = threadIdx.x; j < NBUCK; j += 256) {
            int c = hist[j];
            int ls = j ? a[j - 1] : 0;
            cur[j] = ls;
            int g = c ? atomicAdd(&gcnt[j], c) : 0;
            dlt[j] = j * BUCK_CAP + g - ls;   // absolute dst = dlt + lpos
        }
        __syncthreads();
        // rank-scatter into LDS
        for (int i = threadIdx.x; i < n; i += 256) {
            int r = row[e0 + i];
            int b = r >> BW_SHIFT;
            int lpos = atomicAdd(&cur[b], 1);
            lbuf[lpos] = make_int2(((r & BW_MASK) << 18) | col[e0 + i],
                                   __float_as_int(w[e0 + i]));
            int d = dlt[b] + lpos;
            ldst[lpos] = (d - b * BUCK_CAP < BUCK_CAP) ? d : -1;
        }
        __syncthreads();
        // linear copy-out: bucket-grouped bursts, write-combined in L2
        for (int j = threadIdx.x; j < n; j += 256) {
            int d = ldst[j];
            if (d >= 0) stage[d] = lbuf[j];
        }
        __syncthreads();
    }
}

// scan 293 bucket counts -> bstart[0..NBUCK]; also rs[NUM_NODES] = total
__global__ void bucket_scan(const int* __restrict__ gcnt, int* __restrict__ bstart,
                            int* __restrict__ rs) {
    __shared__ int s0[512], s1[512];
    int tid = threadIdx.x;
    int v = 0;
    if (tid < NBUCK) { v = gcnt[tid]; if (v > BUCK_CAP) v = BUCK_CAP; }
    s0[tid] = v;
    __syncthreads();
    int* a = s0; int* bb = s1;
    for (int off = 1; off < 512; off <<= 1) {
        int x = a[tid];
        if (tid >= off) x += a[tid - off];
        bb[tid] = x;
        __syncthreads();
        int* t = a; a = bb; bb = t;
    }
    if (tid == 0) bstart[0] = 0;
    if (tid < NBUCK) bstart[tid + 1] = a[tid];
    if (tid == 0) rs[NUM_NODES] = a[NBUCK - 1];
}

// Phase B: one block per bucket. LDS 512-row hist + scan -> rs[] + final CSR.
// Plain stores: the 110KB per-bucket window stays L2-resident until filled.
__global__ void __launch_bounds__(256)
bucket_scatter(const int2* __restrict__ stage, const int* __restrict__ gcnt,
               const int* __restrict__ bstart, int* __restrict__ rs,
               int2* __restrict__ csr) {
    __shared__ int s0[BW_ROWS], s1[BW_ROWS];
    int b = blockIdx.x;
    int tid = threadIdx.x;
    int nrec = gcnt[b]; if (nrec > BUCK_CAP) nrec = BUCK_CAP;
    int base = bstart[b];
    const int2* st = stage + (size_t)b * BUCK_CAP;
    int baseRow = b << BW_SHIFT;
    int rows = NUM_NODES - baseRow; if (rows > BW_ROWS) rows = BW_ROWS;

    for (int j = tid; j < BW_ROWS; j += 256) s0[j] = 0;
    __syncthreads();
    for (int i = tid; i < nrec; i += 256) atomicAdd(&s0[st[i].x >> 18], 1);
    __syncthreads();

    int* a = s0; int* bb = s1;
    for (int off = 1; off < BW_ROWS; off <<= 1) {
        for (int j = tid; j < BW_ROWS; j += 256) {
            int x = a[j];
            if (j >= off) x += a[j - off];
            bb[j] = x;
        }
        __syncthreads();
        int* t = a; a = bb; bb = t;
    }

    for (int r = tid; r < rows; r += 256)
        rs[baseRow + r] = base + (r ? a[r - 1] : 0);

    for (int j = tid; j < BW_ROWS; j += 256) bb[j] = 0;   // rank counters
    __syncthreads();
    for (int i = tid; i < nrec; i += 256) {
        int2 rec = st[i];
        int r = rec.x >> 18;
        int rank = atomicAdd(&bb[r], 1);
        csr[base + (r ? a[r - 1] : 0) + rank] = make_int2(rec.x & 0x3FFFF, rec.y);
    }
}

// ---------------- CSR propagate (bf16, 8 lanes/node, ushort8/lane) ----------
// acc[d] = sum_e w[e] * xb[col[e]][d]; out = (addIn + acc)*scale; yb = bf16(acc)
__global__ void __launch_bounds__(256)
lgcn_prop_bf8(const us8v* __restrict__ xb,
              const int* __restrict__ rs,
              const int2* __restrict__ csr,
              us8v* __restrict__ yb,
              const float4* __restrict__ addIn,
              float4* __restrict__ out,
              float scale, int nNodes, int writeY) {
    int gtid = blockIdx.x * blockDim.x + threadIdx.x;
    int node = gtid >> 3;          // 8 lanes per node
    int sub  = threadIdx.x & 7;    // dims [sub*8, sub*8+8)
    if (node >= nNodes) return;
    int s = rs[node], e = rs[node + 1];
    float acc[8] = {0.f, 0.f, 0.f, 0.f, 0.f, 0.f, 0.f, 0.f};

    int base = s;
    for (; base + 8 <= e; base += 8) {
        int2 cw = csr[base + sub];   // 64B coalesced per 8-lane group
#pragma unroll
        for (int j = 0; j < 8; ++j) {
            int bc   = __shfl(cw.x, j, 8);
            float bw = __int_as_float(__shfl(cw.y, j, 8));
            us8v v = xb[(size_t)bc * 8 + sub];   // 16B/lane, 128B/group
#pragma unroll
            for (int k = 0; k < 8; ++k)
                acc[k] = fmaf(bf2f(v[k]), bw, acc[k]);
        }
    }
    if (base < e) {
        int idx = base + sub;
        int2 cw = (idx < e) ? csr[idx] : make_int2(0, 0);
        int nn = e - base;
        for (int j = 0; j < nn; ++j) {
            int bc   = __shfl(cw.x, j, 8);
            float bw = __int_as_float(__shfl(cw.y, j, 8));
            us8v v = xb[(size_t)bc * 8 + sub];
#pragma unroll
            for (int k = 0; k < 8; ++k)
                acc[k] = fmaf(bf2f(v[k]), bw, acc[k]);
        }
    }

    size_t o8 = (size_t)node * 8 + sub;   // ushort8 units
    if (writeY) {
        us8v q;
#pragma unroll
        for (int k = 0; k < 8; ++k) q[k] = f2bf(acc[k]);
        yb[o8] = q;
    }
    size_t o4 = o8 * 2;                   // float4 units
    float4 a0 = addIn[o4];
    float4 a1 = addIn[o4 + 1];
    a0.x = (a0.x + acc[0]) * scale;
    a0.y = (a0.y + acc[1]) * scale;
    a0.z = (a0.z + acc[2]) * scale;
    a0.w = (a0.w + acc[3]) * scale;
    a1.x = (a1.x + acc[4]) * scale;
    a1.y = (a1.y + acc[5]) * scale;
    a1.z = (a1.z + acc[6]) * scale;
    a1.w = (a1.w + acc[7]) * scale;
    out[o4] = a0;
    out[o4 + 1] = a1;
}

// ---------------- fallback (atomic) path kernels ----------------

__global__ void lgcn_init(const float4* __restrict__ emb,
                          float4* __restrict__ x,
                          float4* __restrict__ out, int n4) {
    int i = blockIdx.x * blockDim.x + threadIdx.x;
    int stride = gridDim.x * blockDim.x;
    for (; i < n4; i += stride) {
        float4 v = emb[i];
        x[i] = v;
        out[i] = v;
    }
}

__global__ void lgcn_zero(float4* __restrict__ y, int n4) {
    int i = blockIdx.x * blockDim.x + threadIdx.x;
    int stride = gridDim.x * blockDim.x;
    float4 z = make_float4(0.f, 0.f, 0.f, 0.f);
    for (; i < n4; i += stride) y[i] = z;
}

__global__ void lgcn_edge(const float* __restrict__ x,
                          const float* __restrict__ w,
                          const int* __restrict__ row,
                          const int* __restrict__ col,
                          float* __restrict__ y, int nEdges) {
    int tid = blockIdx.x * blockDim.x + threadIdx.x;
    int wave = tid >> 6;
    int lane = threadIdx.x & 63;
    int nWaves = (gridDim.x * blockDim.x) >> 6;
    for (int e = wave; e < nEdges; e += nWaves) {
        int r = row[e];
        int c = col[e];
        float wt = w[e];
        float v = x[(size_t)c * EMBED_DIM + lane] * wt;
        atomicAdd(&y[(size_t)r * EMBED_DIM + lane], v);
    }
}

__global__ void lgcn_accum(const float4* __restrict__ y,
                           float4* __restrict__ out, float scale, int n4) {
    int i = blockIdx.x * blockDim.x + threadIdx.x;
    int stride = gridDim.x * blockDim.x;
    for (; i < n4; i += stride) {
        float4 o = out[i];
        float4 v = y[i];
        o.x = (o.x + v.x) * scale;
        o.y = (o.y + v.y) * scale;
        o.z = (o.z + v.z) * scale;
        o.w = (o.w + v.w) * scale;
        out[i] = o;
    }
}

// ---------------- launch ----------------

extern "C" void kernel_launch(void* const* d_in, const int* in_sizes, int n_in,
                              void* d_out, int out_size, void* d_ws, size_t ws_size,
                              hipStream_t stream) {
    const float* emb = (const float*)d_in[0];
    const float* ew  = (const float*)d_in[1];
    const int*   row = (const int*)d_in[2];
    const int*   col = (const int*)d_in[3];
    float* out = (float*)d_out;

    const size_t tableElems = (size_t)NUM_NODES * EMBED_DIM;   // 9.6M
    const int n4 = (int)(tableElems / 4);                      // 2.4M

    // workspace layout
    char* ws = (char*)d_ws;
    size_t off = 0;
    auto alloc = [&](size_t bytes) {
        char* p = ws + off;
        off += (bytes + 255) & ~(size_t)255;
        return p;
    };
    ushort4* yAb   = (ushort4*)alloc(tableElems * 2);            // 19.2 MB
    ushort4* yBb   = (ushort4*)alloc(tableElems * 2);            // 19.2 MB
    int2*    csr   = (int2*)   alloc((size_t)N_EDGES * 8);       // 32 MB
    int2*    stage = (int2*)   alloc((size_t)NBUCK * BUCK_CAP * 8); // 37.5 MB
    int*     rs    = (int*)    alloc((size_t)(NUM_NODES + 32) * 4);
    int*     bstart= (int*)    alloc((size_t)(NBUCK + 8) * 4);
    int*     gcnt  = (int*)    alloc((size_t)(NBUCK + 8) * 4);
    size_t need = off;
    // emb_bf aliases stage (19.2 <= 37.5 MB): stage dead after bucket_scatter
    ushort4* embb = (ushort4*)stage;

    if (ws_size >= need) {
        // ---- CSR build ----
        zero_ints<<<2, 256, 0, stream>>>(gcnt, NBUCK);
        bucket_bin2<<<512, 256, 0, stream>>>(row, col, ew, gcnt, stage, N_EDGES);
        bucket_scan<<<1, 512, 0, stream>>>(gcnt, bstart, rs);
        bucket_scatter<<<NBUCK, 256, 0, stream>>>(stage, gcnt, bstart, rs, csr);

        // ---- emb -> bf16 (overwrites stage region, now dead) ----
        conv_bf<<<2048, 256, 0, stream>>>((const float4*)emb, (ushort4*)embb, n4);

        // ---- propagate: 3 layers, 8 lanes per node ----
        const int propBlocks = (NUM_NODES * 8 + 255) / 256;
        // layer 1: x = emb_bf, out = emb + y1, y1 -> yAb
        lgcn_prop_bf8<<<propBlocks, 256, 0, stream>>>((const us8v*)embb, rs, csr,
                                                      (us8v*)yAb,
                                                      (const float4*)emb,
                                                      (float4*)out,
                                                      1.0f, NUM_NODES, 1);
        // layer 2: x = y1, out += y2, y2 -> yBb
        lgcn_prop_bf8<<<propBlocks, 256, 0, stream>>>((const us8v*)yAb, rs, csr,
                                                      (us8v*)yBb,
                                                      (const float4*)out,
                                                      (float4*)out,
                                                      1.0f, NUM_NODES, 1);
        // layer 3: x = y2, out = (out + y3) / 4
        lgcn_prop_bf8<<<propBlocks, 256, 0, stream>>>((const us8v*)yBb, rs, csr,
                                                      (us8v*)yAb,
                                                      (const float4*)out,
                                                      (float4*)out,
                                                      1.0f / (N_LAYERS + 1),
                                                      NUM_NODES, 0);
    } else {
        // ---- fallback: atomic path (round-1 proven), f32 buffers from ws ----
        float* x = (float*)d_ws;
        float* y = x + tableElems;
        lgcn_init<<<2048, 256, 0, stream>>>((const float4*)emb, (float4*)x,
                                            (float4*)out, n4);
        for (int l = 0; l < N_LAYERS; ++l) {
            lgcn_zero<<<2048, 256, 0, stream>>>((float4*)y, n4);
            lgcn_edge<<<4096, 256, 0, stream>>>(x, ew, row, col, y, N_EDGES);
            float scale = (l == N_LAYERS - 1) ? 1.0f / (N_LAYERS + 1) : 1.0f;
            lgcn_accum<<<2048, 256, 0, stream>>>((const float4*)y, (float4*)out,
                                                 scale, n4);
            float* t = x; x = y; y = t;
        }
    }
}